// Round 15
// baseline (393.776 us; speedup 1.0000x reference)
//
#include <hip/hip_runtime.h>

// SelectiveAttnMLA on MI355X (gfx950).
// B=4 S=2048 Hq=16 G=4 D=192 DV=128 BLK=64 NB=32 TOPK=16, out fp32 (8192x2048).
//
// R18: R17 (qb-pair, 8 waves, 142us) + true 1-deep pipeline at SAME residency:
//      - Pbuf (18.4KB) -> R12-verified shuffle P-exchange (frees LDS)
//      - K double-buffered 2x24KB + V 16KB = 65536B exactly; 2 WG/CU = 16 waves
//      - V via 2x b128 reg-detour (+8 VGPR; LDS is the binding constraint)
//      - loop: issue K(nxt)->buf^1 + V(nxt)->regs at TOP; compute(kb) covers
//        the latency; barrier's implicit drain lands them free; writeV; bar2.
//        No wait targets a load younger than one compute phase.
//      - masks via per-lane 2-row reads + shuffles (R10-verified; un_sh gone)
//      T13 defer-max + T5 setprio kept. kv_prep = R14 (at BW floor).

typedef __attribute__((ext_vector_type(8))) _Float16 half8;
typedef __attribute__((ext_vector_type(4))) _Float16 half4;
typedef __attribute__((ext_vector_type(4))) float f32x4;
typedef __attribute__((ext_vector_type(4))) unsigned int u32x4;

__device__ __forceinline__ half8 cvt8s(const float4* p, float s) {
  float4 a = p[0], b = p[1];
  half8 r;
  r[0] = (_Float16)(a.x * s); r[1] = (_Float16)(a.y * s);
  r[2] = (_Float16)(a.z * s); r[3] = (_Float16)(a.w * s);
  r[4] = (_Float16)(b.x * s); r[5] = (_Float16)(b.y * s);
  r[6] = (_Float16)(b.z * s); r[7] = (_Float16)(b.w * s);
  return r;
}

__device__ __forceinline__ void async16(const void* g, void* l) {
  __builtin_amdgcn_global_load_lds(
      (const __attribute__((address_space(1))) void*)g,
      (__attribute__((address_space(3))) void*)l, 16, 0, 0);
}

__device__ __forceinline__ f32x4 vmax4(f32x4 a, f32x4 b) {
  f32x4 r;
  r[0] = fmaxf(a[0], b[0]); r[1] = fmaxf(a[1], b[1]);
  r[2] = fmaxf(a[2], b[2]); r[3] = fmaxf(a[3], b[3]);
  return r;
}

// ---------------- K/V fragment prepass: fused single-barrier structure (R14) ----------------
__global__ __launch_bounds__(256) void kv_prep(const float* __restrict__ k,
                                               const float* __restrict__ v,
                                               _Float16* __restrict__ kf,
                                               _Float16* __restrict__ vf) {
  // disjoint regions: K [64 slots][200] f16 = 25600B, V [64 rows][136] f16 = 17408B
  __shared__ __align__(16) _Float16 kbuf[64 * 200];
  __shared__ __align__(16) _Float16 vbuf[64 * 136];
  int blk = blockIdx.x;               // (b*16+h)*32 + kb
  int bh = blk >> 5, kb = blk & 31;
  int b = bh >> 4, h = bh & 15;
  int tid = threadIdx.x;

  const float* ksrc = k + ((long)(b * 2048 + kb * 64) * 16 + h) * 192;
  const float* vsrc = v + ((long)(b * 2048 + kb * 64) * 16 + h) * 128;

  // K rows stored slot-permuted: slot s=(ntile*16+lm) holds key a=(lm>>2)*16+ntile*4+(lm&3);
  // inverse: s(kk) = ((kk>>2)&3)*16 + ((kk>>4)<<2) + (kk&3).
#pragma unroll
  for (int it = 0; it < 12; ++it) {
    int idx = it * 256 + tid;         // 3072 float4
    int kk = idx / 48, c4 = idx - kk * 48;
    float4 x = *(const float4*)(ksrc + (long)kk * 3072 + c4 * 4);
    int s = ((kk >> 2) & 3) * 16 + ((kk >> 4) << 2) + (kk & 3);
    half4 hx = {(_Float16)x.x, (_Float16)x.y, (_Float16)x.z, (_Float16)x.w};
    *(half4*)(&kbuf[s * 200 + c4 * 4]) = hx;
  }
#pragma unroll
  for (int it = 0; it < 8; ++it) {
    int idx = it * 256 + tid;         // 2048 float4
    int kk = idx >> 5, c4 = idx & 31;
    float4 x = *(const float4*)(vsrc + (long)kk * 2048 + c4 * 4);
    half4 hx = {(_Float16)x.x, (_Float16)x.y, (_Float16)x.z, (_Float16)x.w};
    *(half4*)(&vbuf[kk * 136 + c4 * 4]) = hx;
  }
  __syncthreads();                    // the only barrier

  _Float16* kdst = kf + (long)blk * 12288;
#pragma unroll
  for (int it = 0; it < 6; ++it) {
    int oct = it * 256 + tid;         // 1536 octets: b128 LDS read -> b128 global write
    int frag = oct >> 6, lane = oct & 63;
    int ntile = frag / 6, kc = frag - ntile * 6;
    int s = ntile * 16 + (lane & 15);
    int d = kc * 32 + ((lane >> 4) << 3);
    *(half8*)(kdst + (long)oct * 8) = *(const half8*)(&kbuf[s * 200 + d]);
  }

  _Float16* vdst = vf + (long)blk * 8192;
#pragma unroll
  for (int it = 0; it < 4; ++it) {
    int oct = it * 256 + tid;         // 1024 octets
    int frag = oct >> 6, lane = oct & 63;
    int n0 = frag >> 1, kc = frag & 1;
    int dv = n0 * 16 + (lane & 15);
    int kbase = kc * 32 + ((lane >> 4) << 3);
    half8 o;
#pragma unroll
    for (int j = 0; j < 8; ++j) o[j] = vbuf[(kbase + j) * 136 + dv];
    *(half8*)(vdst + (long)oct * 8) = o;
  }
}

// ---------------- main attention: qb-pair, K-dbuf pipeline, shuffle-P ----------------
__global__ __launch_bounds__(512) void attn_main(const float* __restrict__ q,
                                                 const int* __restrict__ idx,
                                                 const _Float16* __restrict__ kf,
                                                 const _Float16* __restrict__ vf,
                                                 float* __restrict__ out) {
  constexpr float SCL = 0.07216878364870322f * 1.4426950408889634f;  // sm_scale*log2e
  int id = (int)blockIdx.x;           // [0,1024)
  int u = 15 - (id >> 6);             // pair index, heavy pairs first
  int bh = id & 63;
  int h = bh & 15, b = bh >> 4, g = h >> 2;
  int qlo = 2 * u, qhi = 2 * u + 1;
  int tid = threadIdx.x;
  int w = tid >> 6, L = tid & 63;     // 8 waves
  int Lm = L & 15, Lq = L >> 4;
  int tile = w >> 2;                  // 0 -> qb=qlo, 1 -> qb=qhi
  int m0 = (w & 3) * 16;              // within-tile row offset
  int myqb = qlo + tile;
  int t0 = b * 2048 + qlo * 64;
  long trow = t0 + tile * 64 + m0 + Lm;   // this lane's global query row

  __shared__ __align__(16) char sh_k[2][24576];  // K frag double buffer
  __shared__ __align__(16) char sh_v[16384];     // V frags = 65536B total (2 WG/CU)

  // Q as B-operand: col = Lm (query row), k-slots = d
  half8 qa[6];
  const float* qrow = q + (trow * 16 + h) * 192;
#pragma unroll
  for (int c = 0; c < 6; ++c) qa[c] = cvt8s((const float4*)(qrow + c * 32 + Lq * 8), SCL);

  // masks without LDS (R10-verified): lane L covers pair rows L and L+64.
  unsigned rm0 = 0, rm1 = 0;
  {
    const int4* ip0 = (const int4*)(idx + ((long)(t0 + L) * 4 + g) * 16);
    const int4* ip1 = (const int4*)(idx + ((long)(t0 + 64 + L) * 4 + g) * 16);
#pragma unroll
    for (int e = 0; e < 4; ++e) {
      int4 i0 = ip0[e], i1 = ip1[e];
      rm0 |= (1u << i0.x) | (1u << i0.y) | (1u << i0.z) | (1u << i0.w);
      rm1 |= (1u << i1.x) | (1u << i1.y) | (1u << i1.z) | (1u << i1.w);
    }
  }
  unsigned bm = rm0 | rm1;
#pragma unroll
  for (int o = 1; o < 64; o <<= 1) bm |= __shfl_xor(bm, o, 64);   // 128-row union
  unsigned rmT = tile ? rm1 : rm0;
  unsigned g16 = rmT;                  // 16-lane-group OR
  g16 |= __shfl_xor(g16, 1);
  g16 |= __shfl_xor(g16, 2);
  g16 |= __shfl_xor(g16, 4);
  g16 |= __shfl_xor(g16, 8);
  unsigned un = __shfl(g16, m0, 64);   // my wave's 16-row union
  unsigned mrow = __shfl(rmT, m0 + Lm, 64);  // my query row's mask
  unsigned bmask = bm & ((2u << qhi) - 1);   // bits 0..qhi (qhi=31 wraps all-ones)

  f32x4 Oacc[8];                      // O^T tiles: row = dv, col = q (Lm)
#pragma unroll
  for (int n0 = 0; n0 < 8; ++n0) Oacc[n0] = (f32x4){0.f, 0.f, 0.f, 0.f};
  float m_i = -1e30f, l_i = 0.f;      // scalar per lane (row-local)

  const char* kfb = (const char*)(kf + (long)((b * 16 + h) * 32) * 12288);
  const char* vfb = (const char*)(vf + (long)((b * 16 + h) * 32) * 8192);

  auto stageK = [&](int kb2, char* dst) {
    const char* kg = kfb + (long)kb2 * 24576;
#pragma unroll
    for (int c = 0; c < 3; ++c) {      // 24 channels over 8 waves
      int ch = w + c * 8;
      async16(kg + ch * 1024 + L * 16, dst + ch * 1024);
    }
  };
  u32x4 vreg[2];                       // V reg-detour (2 channels/wave of 16)
  auto loadVreg = [&](int kb2) {
    const char* vg = vfb + (long)kb2 * 16384;
#pragma unroll
    for (int c = 0; c < 2; ++c)
      vreg[c] = *(const u32x4*)(vg + (w + c * 8) * 1024 + L * 16);
  };
  auto writeV = [&]() {
#pragma unroll
    for (int c = 0; c < 2; ++c)
      *(u32x4*)(sh_v + (w + c * 8) * 1024 + L * 16) = vreg[c];
  };

  const half8* lvf = (const half8*)sh_v;

  auto compute = [&](int kb, bool lastb, const half8* lkf) __attribute__((always_inline)) {
    // S^T = K Q^T: lane holds scores of query Lm for actual keys Lq*16 + nt*4 + i
    f32x4 S[4];
    __builtin_amdgcn_s_setprio(1);
#pragma unroll
    for (int nt = 0; nt < 4; ++nt) {
      f32x4 acc = {0.f, 0.f, 0.f, 0.f};
#pragma unroll
      for (int c = 0; c < 6; ++c)
        acc = __builtin_amdgcn_mfma_f32_16x16x32_f16(lkf[(nt * 6 + c) * 64 + L], qa[c], acc, 0, 0, 0);
      S[nt] = acc;
    }
    __builtin_amdgcn_s_setprio(0);

    float p[4][4];
    float msel = ((mrow >> kb) & 1u) ? 1.0f : 0.0f;
    if (!lastb) {
      // selection via per-row 0/1 multiply; inflated row-max from unselected
      // rows is exact (softmax shift-invariance), p*0 kills the values.
      f32x4 t = vmax4(vmax4(S[0], S[1]), vmax4(S[2], S[3]));
      float rmax = fmaxf(fmaxf(t[0], t[1]), fmaxf(t[2], t[3]));
      rmax = fmaxf(rmax, __shfl_xor(rmax, 16));
      rmax = fmaxf(rmax, __shfl_xor(rmax, 32));
      // T13 defer-max: tolerate P up to 2^8 before paying the rescale.
      if (__any(rmax > m_i + 8.0f)) {
        float mn = fmaxf(m_i, rmax);
        float av = __builtin_amdgcn_exp2f(m_i - mn);
        m_i = mn;
        l_i *= av;
#pragma unroll
        for (int n0 = 0; n0 < 8; ++n0) Oacc[n0] *= av;
      }
      float ps[4];
#pragma unroll
      for (int nt = 0; nt < 4; ++nt) {
        float s0 = 0.f, s1 = 0.f;
#pragma unroll
        for (int i = 0; i < 4; i += 2) {
          float a = __builtin_amdgcn_exp2f(S[nt][i] - m_i) * msel;
          float c = __builtin_amdgcn_exp2f(S[nt][i + 1] - m_i) * msel;
          p[nt][i] = a; p[nt][i + 1] = c;
          s0 += a; s1 += c;
        }
        ps[nt] = s0 + s1;
      }
      float psum = (ps[0] + ps[1]) + (ps[2] + ps[3]);
      psum += __shfl_xor(psum, 16);
      psum += __shfl_xor(psum, 32);
      l_i += psum;
    } else {
      // diagonal block: full per-element causal+selection masking
      float sc[4][4];
      float rmax = -1e30f;
#pragma unroll
      for (int nt = 0; nt < 4; ++nt)
#pragma unroll
        for (int i = 0; i < 4; ++i) {
          int key = Lq * 16 + nt * 4 + i;   // actual key (permuted kf order)
          bool ok = (msel != 0.f) && (key <= m0 + Lm);
          float v = ok ? S[nt][i] : -1e30f;
          sc[nt][i] = v;
          rmax = fmaxf(rmax, v);
        }
      rmax = fmaxf(rmax, __shfl_xor(rmax, 16));
      rmax = fmaxf(rmax, __shfl_xor(rmax, 32));
      float mn = fmaxf(m_i, rmax);
      float av = __builtin_amdgcn_exp2f(m_i - mn);
      m_i = mn;
      float ps[4];
#pragma unroll
      for (int nt = 0; nt < 4; ++nt) {
        float s0 = 0.f;
#pragma unroll
        for (int i = 0; i < 4; ++i) {
          float a = __builtin_amdgcn_exp2f(sc[nt][i] - mn);
          p[nt][i] = a;
          s0 += a;
        }
        ps[nt] = s0;
      }
      float psum = (ps[0] + ps[1]) + (ps[2] + ps[3]);
      psum += __shfl_xor(psum, 16);
      psum += __shfl_xor(psum, 32);
      l_i = l_i * av + psum;
#pragma unroll
      for (int n0 = 0; n0 < 8; ++n0) Oacc[n0] *= av;
    }

    // pack P to f16 pairs: word t covers keys Lq*16 + 2t
    unsigned w8[8];
#pragma unroll
    for (int nt = 0; nt < 4; ++nt) {
      w8[2 * nt]     = __builtin_bit_cast(unsigned, __builtin_amdgcn_cvt_pkrtz(p[nt][0], p[nt][1]));
      w8[2 * nt + 1] = __builtin_bit_cast(unsigned, __builtin_amdgcn_cvt_pkrtz(p[nt][2], p[nt][3]));
    }
    // cross-lane exchange (R12-verified, no LDS): dest (Lm,Lq),kc needs keys
    // kc*32+Lq*8+2e from src lane ((Lq>>1)+2kc)*16+Lm, src word (Lq&1)*4+e.
    half8 pfr[2];
#pragma unroll
    for (int kc = 0; kc < 2; ++kc) {
      int src = ((Lq >> 1) + 2 * kc) * 16 + Lm;
      u32x4 d;
#pragma unroll
      for (int e = 0; e < 4; ++e) {
        unsigned lo = (unsigned)__shfl((int)w8[e], src, 64);
        unsigned hi = (unsigned)__shfl((int)w8[e + 4], src, 64);
        d[e] = (Lq & 1) ? hi : lo;
      }
      pfr[kc] = __builtin_bit_cast(half8, d);
    }

    // PV: O^T += V^T P^T, V from LDS
    __builtin_amdgcn_s_setprio(1);
#pragma unroll
    for (int kc = 0; kc < 2; ++kc)
#pragma unroll
      for (int n0 = 0; n0 < 8; ++n0)
        Oacc[n0] = __builtin_amdgcn_mfma_f32_16x16x32_f16(lvf[(n0 * 2 + kc) * 64 + L], pfr[kc], Oacc[n0], 0, 0, 0);
    __builtin_amdgcn_s_setprio(0);
  };

  // prologue: block 0 always selected.
  stageK(0, sh_k[0]);
  loadVreg(0);
  __syncthreads();                    // implicit drain: K(0) landed, vreg ready
  writeV();
  __syncthreads();                    // sh_v visible

  unsigned rem = bmask;               // bit 0 always set
  int kb = 0, cur = 0;
  for (;;) {
    rem &= rem - 1;
    int nxt = rem ? (int)__builtin_ctz(rem) : -1;
    if (nxt >= 0) {
      stageK(nxt, sh_k[cur ^ 1]);     // 3 async16, in flight through compute
      loadVreg(nxt);                  // 2 b128 loads, likewise
    }

    if (kb <= myqb && ((un >> kb) & 1u))
      compute(kb, kb == myqb, (const half8*)sh_k[cur]);

    __syncthreads();                  // drains VM (covered by compute) + LDS reads
    if (nxt < 0) break;
    writeV();                         // sh_v <- V(nxt)
    __syncthreads();                  // visible; sh_k[cur^1] ready for next QK
    cur ^= 1;
    kb = nxt;
  }

  float inv = 1.f / l_i;
  float* orow = out + trow * 2048 + h * 128 + Lq * 4;
#pragma unroll
  for (int n0 = 0; n0 < 8; ++n0) {
    f32x4 o = Oacc[n0] * inv;
    *(f32x4*)(orow + n0 * 16) = o;
  }
}

extern "C" void kernel_launch(void* const* d_in, const int* in_sizes, int n_in,
                              void* d_out, int out_size, void* d_ws, size_t ws_size,
                              hipStream_t stream) {
  const float* q = (const float*)d_in[0];
  const float* k = (const float*)d_in[1];
  const float* v = (const float*)d_in[2];
  const int* idx = (const int*)d_in[3];
  _Float16* kf = (_Float16*)d_ws;                       // 2048 blk * 12288 f16 = 50.3 MB
  _Float16* vf = kf + (size_t)2048 * 12288;             // 2048 blk * 8192  f16 = 33.6 MB
  float* out = (float*)d_out;
  kv_prep<<<2048, 256, 0, stream>>>(k, v, kf, vf);
  attn_main<<<1024, 512, 0, stream>>>(q, idx, kf, vf, out);
}

// Round 17
// 380.669 us; speedup vs baseline: 1.0344x; 1.0344x over previous
//
#include <hip/hip_runtime.h>

// SelectiveAttnMLA on MI355X (gfx950).
// B=4 S=2048 Hq=16 G=4 D=192 DV=128 BLK=64 NB=32 TOPK=16, out fp32 (8192x2048).
//
// R20 = R17 verbatim (session champion: 385.0us total, attn 142us).
//      qb-pair fusion at 8 waves: one 512-thread WG handles qb={2u,2u+1};
//      waves 0-3 own tile qlo, waves 4-7 own tile qhi; ONE staged K/V tile
//      serves both. Sync = drain-per-block (the 16-wave interleave hides the
//      drain; every explicit pipeline variant R5-R19 regressed or raced).
//      Body = Pbuf b128 P-exchange + T13 defer-max + T5 setprio.
//      kv_prep = R14 single-barrier fused (measured at BW floor).

typedef __attribute__((ext_vector_type(8))) _Float16 half8;
typedef __attribute__((ext_vector_type(4))) _Float16 half4;
typedef __attribute__((ext_vector_type(4))) float f32x4;
typedef __attribute__((ext_vector_type(4))) unsigned int u32x4;

__device__ __forceinline__ half8 cvt8s(const float4* p, float s) {
  float4 a = p[0], b = p[1];
  half8 r;
  r[0] = (_Float16)(a.x * s); r[1] = (_Float16)(a.y * s);
  r[2] = (_Float16)(a.z * s); r[3] = (_Float16)(a.w * s);
  r[4] = (_Float16)(b.x * s); r[5] = (_Float16)(b.y * s);
  r[6] = (_Float16)(b.z * s); r[7] = (_Float16)(b.w * s);
  return r;
}

__device__ __forceinline__ void async16(const void* g, void* l) {
  __builtin_amdgcn_global_load_lds(
      (const __attribute__((address_space(1))) void*)g,
      (__attribute__((address_space(3))) void*)l, 16, 0, 0);
}

__device__ __forceinline__ f32x4 vmax4(f32x4 a, f32x4 b) {
  f32x4 r;
  r[0] = fmaxf(a[0], b[0]); r[1] = fmaxf(a[1], b[1]);
  r[2] = fmaxf(a[2], b[2]); r[3] = fmaxf(a[3], b[3]);
  return r;
}

// ---------------- K/V fragment prepass: fused single-barrier structure (R14) ----------------
__global__ __launch_bounds__(256) void kv_prep(const float* __restrict__ k,
                                               const float* __restrict__ v,
                                               _Float16* __restrict__ kf,
                                               _Float16* __restrict__ vf) {
  // disjoint regions: K [64 slots][200] f16 = 25600B, V [64 rows][136] f16 = 17408B
  __shared__ __align__(16) _Float16 kbuf[64 * 200];
  __shared__ __align__(16) _Float16 vbuf[64 * 136];
  int blk = blockIdx.x;               // (b*16+h)*32 + kb
  int bh = blk >> 5, kb = blk & 31;
  int b = bh >> 4, h = bh & 15;
  int tid = threadIdx.x;

  const float* ksrc = k + ((long)(b * 2048 + kb * 64) * 16 + h) * 192;
  const float* vsrc = v + ((long)(b * 2048 + kb * 64) * 16 + h) * 128;

  // K rows stored slot-permuted: slot s=(ntile*16+lm) holds key a=(lm>>2)*16+ntile*4+(lm&3);
  // inverse: s(kk) = ((kk>>2)&3)*16 + ((kk>>4)<<2) + (kk&3).
#pragma unroll
  for (int it = 0; it < 12; ++it) {
    int idx = it * 256 + tid;         // 3072 float4
    int kk = idx / 48, c4 = idx - kk * 48;
    float4 x = *(const float4*)(ksrc + (long)kk * 3072 + c4 * 4);
    int s = ((kk >> 2) & 3) * 16 + ((kk >> 4) << 2) + (kk & 3);
    half4 hx = {(_Float16)x.x, (_Float16)x.y, (_Float16)x.z, (_Float16)x.w};
    *(half4*)(&kbuf[s * 200 + c4 * 4]) = hx;
  }
#pragma unroll
  for (int it = 0; it < 8; ++it) {
    int idx = it * 256 + tid;         // 2048 float4
    int kk = idx >> 5, c4 = idx & 31;
    float4 x = *(const float4*)(vsrc + (long)kk * 2048 + c4 * 4);
    half4 hx = {(_Float16)x.x, (_Float16)x.y, (_Float16)x.z, (_Float16)x.w};
    *(half4*)(&vbuf[kk * 136 + c4 * 4]) = hx;
  }
  __syncthreads();                    // the only barrier

  _Float16* kdst = kf + (long)blk * 12288;
#pragma unroll
  for (int it = 0; it < 6; ++it) {
    int oct = it * 256 + tid;         // 1536 octets: b128 LDS read -> b128 global write
    int frag = oct >> 6, lane = oct & 63;
    int ntile = frag / 6, kc = frag - ntile * 6;
    int s = ntile * 16 + (lane & 15);
    int d = kc * 32 + ((lane >> 4) << 3);
    *(half8*)(kdst + (long)oct * 8) = *(const half8*)(&kbuf[s * 200 + d]);
  }

  _Float16* vdst = vf + (long)blk * 8192;
#pragma unroll
  for (int it = 0; it < 4; ++it) {
    int oct = it * 256 + tid;         // 1024 octets
    int frag = oct >> 6, lane = oct & 63;
    int n0 = frag >> 1, kc = frag & 1;
    int dv = n0 * 16 + (lane & 15);
    int kbase = kc * 32 + ((lane >> 4) << 3);
    half8 o;
#pragma unroll
    for (int j = 0; j < 8; ++j) o[j] = vbuf[(kbase + j) * 136 + dv];
    *(half8*)(vdst + (long)oct * 8) = o;
  }
}

// ---------------- main attention: qb-pair, 8 waves, champion sync/body ----------------
__global__ __launch_bounds__(512) void attn_main(const float* __restrict__ q,
                                                 const int* __restrict__ idx,
                                                 const _Float16* __restrict__ kf,
                                                 const _Float16* __restrict__ vf,
                                                 float* __restrict__ out) {
  constexpr float SCL = 0.07216878364870322f * 1.4426950408889634f;  // sm_scale*log2e
  int id = (int)blockIdx.x;           // [0,1024)
  int u = 15 - (id >> 6);             // pair index, heavy pairs first
  int bh = id & 63;
  int h = bh & 15, b = bh >> 4, g = h >> 2;
  int qlo = 2 * u, qhi = 2 * u + 1;
  int tid = threadIdx.x;
  int w = tid >> 6, L = tid & 63;     // 8 waves
  int Lm = L & 15, Lq = L >> 4;
  int tile = w >> 2;                  // 0 -> qb=qlo, 1 -> qb=qhi
  int m0 = (w & 3) * 16;              // within-tile row offset
  int myqb = qlo + tile;
  int t0 = b * 2048 + qlo * 64;
  long trow = t0 + tile * 64 + m0 + Lm;   // this lane's global query row

  __shared__ __align__(16) char sh_kv[40960];          // 24KB K + 16KB V frags
  __shared__ __align__(16) _Float16 Pbuf[8][16 * 72];  // per-wave [q][key], stride 144B
  __shared__ unsigned un_sh[8];
  char* lk = sh_kv;
  char* lv = sh_kv + 24576;

  // Q as B-operand: col = Lm (query row), k-slots = d
  half8 qa[6];
  const float* qrow = q + (trow * 16 + h) * 192;
#pragma unroll
  for (int c = 0; c < 6; ++c) qa[c] = cvt8s((const float4*)(qrow + c * 32 + Lq * 8), SCL);

  // per-lane selection mask for THIS lane's query row
  unsigned mrow = 0;
  {
    const int4* ip = (const int4*)(idx + (trow * 4 + g) * 16);
#pragma unroll
    for (int e = 0; e < 4; ++e) {
      int4 iv = ip[e];
      mrow |= (1u << iv.x) | (1u << iv.y) | (1u << iv.z) | (1u << iv.w);
    }
  }
  unsigned un = mrow;
#pragma unroll
  for (int o = 32; o; o >>= 1) un |= __shfl_xor(un, o, 64);   // wave's 16-row union
  if (L == 0) un_sh[w] = un;
  __syncthreads();
  unsigned bm = un_sh[0] | un_sh[1] | un_sh[2] | un_sh[3] |
                un_sh[4] | un_sh[5] | un_sh[6] | un_sh[7];
  unsigned bmask = bm & ((2u << qhi) - 1);  // bits 0..qhi (qhi=31 wraps to all-ones)

  f32x4 Oacc[8];                      // O^T tiles: row = dv, col = q (Lm)
#pragma unroll
  for (int n0 = 0; n0 < 8; ++n0) Oacc[n0] = (f32x4){0.f, 0.f, 0.f, 0.f};
  float m_i = -1e30f, l_i = 0.f;      // scalar per lane (row-local)

  const char* kfb = (const char*)(kf + (long)((b * 16 + h) * 32) * 12288);
  const char* vfb = (const char*)(vf + (long)((b * 16 + h) * 32) * 8192);
  _Float16* pw = &Pbuf[w][0];
  const half8* lkf = (const half8*)lk;
  const half8* lvf = (const half8*)lv;

  auto stage = [&](int kb) {
    const char* kg = kfb + (long)kb * 24576;
    const char* vg = vfb + (long)kb * 16384;
#pragma unroll
    for (int c = 0; c < 3; ++c) {     // 24 K channels over 8 waves
      int ch = w + c * 8;
      async16(kg + ch * 1024 + L * 16, lk + ch * 1024);
    }
#pragma unroll
    for (int c = 0; c < 2; ++c) {     // 16 V channels over 8 waves
      int ch = w + c * 8;
      async16(vg + ch * 1024 + L * 16, lv + ch * 1024);
    }
  };

  auto compute = [&](int kb, bool lastb) __attribute__((always_inline)) {
    // S^T = K Q^T: lane holds scores of query Lm for actual keys Lq*16 + nt*4 + i
    f32x4 S[4];
    __builtin_amdgcn_s_setprio(1);
#pragma unroll
    for (int nt = 0; nt < 4; ++nt) {
      f32x4 acc = {0.f, 0.f, 0.f, 0.f};
#pragma unroll
      for (int c = 0; c < 6; ++c)
        acc = __builtin_amdgcn_mfma_f32_16x16x32_f16(lkf[(nt * 6 + c) * 64 + L], qa[c], acc, 0, 0, 0);
      S[nt] = acc;
    }
    __builtin_amdgcn_s_setprio(0);

    float p[4][4];
    float msel = ((mrow >> kb) & 1u) ? 1.0f : 0.0f;
    if (!lastb) {
      // selection via per-row 0/1 multiply; inflated row-max from unselected
      // rows is exact (softmax shift-invariance), p*0 kills the values.
      f32x4 t = vmax4(vmax4(S[0], S[1]), vmax4(S[2], S[3]));
      float rmax = fmaxf(fmaxf(t[0], t[1]), fmaxf(t[2], t[3]));
      rmax = fmaxf(rmax, __shfl_xor(rmax, 16));
      rmax = fmaxf(rmax, __shfl_xor(rmax, 32));
      // T13 defer-max: tolerate P up to 2^8 before paying the rescale.
      if (__any(rmax > m_i + 8.0f)) {
        float mn = fmaxf(m_i, rmax);
        float av = __builtin_amdgcn_exp2f(m_i - mn);
        m_i = mn;
        l_i *= av;
#pragma unroll
        for (int n0 = 0; n0 < 8; ++n0) Oacc[n0] *= av;
      }
      float ps[4];
#pragma unroll
      for (int nt = 0; nt < 4; ++nt) {
        float s0 = 0.f, s1 = 0.f;
#pragma unroll
        for (int i = 0; i < 4; i += 2) {
          float a = __builtin_amdgcn_exp2f(S[nt][i] - m_i) * msel;
          float c = __builtin_amdgcn_exp2f(S[nt][i + 1] - m_i) * msel;
          p[nt][i] = a; p[nt][i + 1] = c;
          s0 += a; s1 += c;
        }
        ps[nt] = s0 + s1;
      }
      float psum = (ps[0] + ps[1]) + (ps[2] + ps[3]);
      psum += __shfl_xor(psum, 16);
      psum += __shfl_xor(psum, 32);
      l_i += psum;
    } else {
      // diagonal block: full per-element causal+selection masking
      float sc[4][4];
      float rmax = -1e30f;
#pragma unroll
      for (int nt = 0; nt < 4; ++nt)
#pragma unroll
        for (int i = 0; i < 4; ++i) {
          int key = Lq * 16 + nt * 4 + i;   // actual key (permuted kf order)
          bool ok = (msel != 0.f) && (key <= m0 + Lm);
          float v = ok ? S[nt][i] : -1e30f;
          sc[nt][i] = v;
          rmax = fmaxf(rmax, v);
        }
      rmax = fmaxf(rmax, __shfl_xor(rmax, 16));
      rmax = fmaxf(rmax, __shfl_xor(rmax, 32));
      float mn = fmaxf(m_i, rmax);
      float av = __builtin_amdgcn_exp2f(m_i - mn);
      m_i = mn;
      float ps[4];
#pragma unroll
      for (int nt = 0; nt < 4; ++nt) {
        float s0 = 0.f;
#pragma unroll
        for (int i = 0; i < 4; ++i) {
          float a = __builtin_amdgcn_exp2f(sc[nt][i] - mn);
          p[nt][i] = a;
          s0 += a;
        }
        ps[nt] = s0;
      }
      float psum = (ps[0] + ps[1]) + (ps[2] + ps[3]);
      psum += __shfl_xor(psum, 16);
      psum += __shfl_xor(psum, 32);
      l_i = l_i * av + psum;
#pragma unroll
      for (int n0 = 0; n0 < 8; ++n0) Oacc[n0] *= av;
    }

    // P row is lane-contiguous: pack to f16 pairs, 2x b128 store, 2x b128 read.
    asm volatile("s_waitcnt lgkmcnt(0)" ::: "memory");  // WAR vs last iter's reads
    u32x4 w0, w1;
    {
      auto c00 = __builtin_amdgcn_cvt_pkrtz(p[0][0], p[0][1]);
      auto c01 = __builtin_amdgcn_cvt_pkrtz(p[0][2], p[0][3]);
      auto c10 = __builtin_amdgcn_cvt_pkrtz(p[1][0], p[1][1]);
      auto c11 = __builtin_amdgcn_cvt_pkrtz(p[1][2], p[1][3]);
      auto c20 = __builtin_amdgcn_cvt_pkrtz(p[2][0], p[2][1]);
      auto c21 = __builtin_amdgcn_cvt_pkrtz(p[2][2], p[2][3]);
      auto c30 = __builtin_amdgcn_cvt_pkrtz(p[3][0], p[3][1]);
      auto c31 = __builtin_amdgcn_cvt_pkrtz(p[3][2], p[3][3]);
      w0[0] = __builtin_bit_cast(unsigned, c00); w0[1] = __builtin_bit_cast(unsigned, c01);
      w0[2] = __builtin_bit_cast(unsigned, c10); w0[3] = __builtin_bit_cast(unsigned, c11);
      w1[0] = __builtin_bit_cast(unsigned, c20); w1[1] = __builtin_bit_cast(unsigned, c21);
      w1[2] = __builtin_bit_cast(unsigned, c30); w1[3] = __builtin_bit_cast(unsigned, c31);
    }
    *(u32x4*)(pw + Lm * 72 + Lq * 16) = w0;
    *(u32x4*)(pw + Lm * 72 + Lq * 16 + 8) = w1;
    asm volatile("s_waitcnt lgkmcnt(0)" ::: "memory");  // RAW: writes visible

    __builtin_amdgcn_s_setprio(1);
#pragma unroll
    for (int kc = 0; kc < 2; ++kc) {
      half8 pfr = *(const half8*)(pw + Lm * 72 + kc * 32 + Lq * 8);  // B: P^T k-slots
#pragma unroll
      for (int n0 = 0; n0 < 8; ++n0)
        Oacc[n0] = __builtin_amdgcn_mfma_f32_16x16x32_f16(lvf[(n0 * 2 + kc) * 64 + L], pfr, Oacc[n0], 0, 0, 0);
    }
    __builtin_amdgcn_s_setprio(0);
  };

  // kb ascends over the pair's union mask; block 0 always selected.
  unsigned rem = bmask;
  while (rem) {
    int kb = (int)__builtin_ctz(rem);
    rem &= rem - 1;
    stage(kb);
    asm volatile("s_waitcnt vmcnt(0)" ::: "memory");
    __syncthreads();
    if (kb <= myqb && ((un >> kb) & 1u)) compute(kb, kb == myqb);
    __syncthreads();
  }

  float inv = 1.f / l_i;
  float* orow = out + trow * 2048 + h * 128 + Lq * 4;
#pragma unroll
  for (int n0 = 0; n0 < 8; ++n0) {
    f32x4 o = Oacc[n0] * inv;
    *(f32x4*)(orow + n0 * 16) = o;
  }
}

extern "C" void kernel_launch(void* const* d_in, const int* in_sizes, int n_in,
                              void* d_out, int out_size, void* d_ws, size_t ws_size,
                              hipStream_t stream) {
  const float* q = (const float*)d_in[0];
  const float* k = (const float*)d_in[1];
  const float* v = (const float*)d_in[2];
  const int* idx = (const int*)d_in[3];
  _Float16* kf = (_Float16*)d_ws;                       // 2048 blk * 12288 f16 = 50.3 MB
  _Float16* vf = kf + (size_t)2048 * 12288;             // 2048 blk * 8192  f16 = 33.6 MB
  float* out = (float*)d_out;
  kv_prep<<<2048, 256, 0, stream>>>(k, v, kf, vf);
  attn_main<<<1024, 512, 0, stream>>>(q, idx, kf, vf, out);
}